// Round 8
// baseline (100.252 us; speedup 1.0000x reference)
//
#include <hip/hip_runtime.h>
#include <math.h>
#include <stdint.h>

#define T_SEQ 2048
#define BATCH 4
#define DMODEL 128
#define DFF 512
#define NHEAD 8
#define EHEAD 16

#define QSCALE (0.022097086912079608f * 1.4426950408889634f)   // rsqrt(T) * log2(e)

typedef __attribute__((ext_vector_type(8))) short bf16x8;
typedef __attribute__((ext_vector_type(4))) short bf16x4;
typedef __attribute__((ext_vector_type(4))) float f32x4;

__device__ __forceinline__ short f2bf(float f) {            // RNE
    uint32_t u = __float_as_uint(f);
    u = u + 0x7FFF + ((u >> 16) & 1);
    return (short)(u >> 16);
}
__device__ __forceinline__ short bftrunc(float f) {         // truncate (cheap)
    return (short)(__float_as_uint(f) >> 16);
}
__device__ __forceinline__ float bf2f(short s) {
    return __uint_as_float(((uint32_t)(unsigned short)s) << 16);
}
__device__ __forceinline__ float exp2_fast(float x) {       // raw v_exp_f32
#if __has_builtin(__builtin_amdgcn_exp2f)
    return __builtin_amdgcn_exp2f(x);
#else
    float r; asm("v_exp_f32 %0, %1" : "=v"(r) : "v"(x)); return r;
#endif
}

#define MFMA16(A, B, C) __builtin_amdgcn_mfma_f32_16x16x32_bf16(A, B, C, 0, 0, 0)

__device__ __forceinline__ void gload16(const void* g, void* l) {
    __builtin_amdgcn_global_load_lds(
        (const __attribute__((address_space(1))) void*)g,
        (__attribute__((address_space(3))) void*)l, 16, 0, 0);
}

// ---------------------------------------------------------------------------
// K0: xpe = x + PE (fp32 + bf16 copies); transpose+convert all weights to bf16
// ---------------------------------------------------------------------------
__global__ __launch_bounds__(256) void k_pre(const float* __restrict__ x,
                                             const float* __restrict__ WQ,
                                             const float* __restrict__ WK,
                                             const float* __restrict__ WV,
                                             const float* __restrict__ W1,
                                             const float* __restrict__ W2,
                                             float* __restrict__ xpe,
                                             short* __restrict__ xpe16,
                                             short* __restrict__ Wqkvt,
                                             short* __restrict__ W1t,
                                             short* __restrict__ W2t) {
    int bid = blockIdx.x;
    int tid = threadIdx.x;
    if (bid < 4096) {                       // PE over B*T*D = 1M
        int idx = bid * 256 + tid;
        int f = idx & (DMODEL - 1);
        int t = (idx >> 7) & (T_SEQ - 1);
        float dv = __expf(-(float)(f & ~1) * (9.210340371976184f / 128.0f));
        float ang = (float)t * dv;
        float pe = (f & 1) ? __cosf(ang) : __sinf(ang);
        float v = x[idx] + pe;
        xpe[idx] = v;
        xpe16[idx] = f2bf(v);
    } else if (bid < 4288) {                // WQ/WK/WV -> [n][k] bf16
        int m = (bid - 4096) >> 6;
        int o = ((bid - 4096) & 63) * 256 + tid;      // 0..16383
        int n = o >> 7, k = o & 127;
        const float* W = (m == 0) ? WQ : (m == 1) ? WK : WV;
        Wqkvt[m * 16384 + o] = f2bf(W[k * 128 + n]);
    } else if (bid < 4544) {                // W1 [128][512] -> W1t [512][128]
        int o = (bid - 4288) * 256 + tid;   // 0..65535
        int n = o >> 7, k = o & 127;
        W1t[o] = f2bf(W1[k * 512 + n]);
    } else {                                // W2 [512][128] -> W2t [128][512]
        int o = (bid - 4544) * 256 + tid;   // 0..65535
        int n = o >> 9, k = o & 511;
        W2t[o] = f2bf(W2[k * 128 + n]);
    }
}

// ---------------------------------------------------------------------------
// K1: QKV projection: bf16 MFMA GEMM, W in registers (Wt[n][k] bf16).
// z=0: Qh[hb][t][16] *= QSCALE; z=1: Kh[hb][t][16]; z=2: Vs[hb][e][T]
// ---------------------------------------------------------------------------
__global__ __launch_bounds__(256) void k_qkv(const short* __restrict__ xpe16,
                                             const short* __restrict__ Wqkvt,
                                             short* __restrict__ Qh,
                                             short* __restrict__ Kh,
                                             short* __restrict__ Vs) {
    int z = blockIdx.y;
    const short* Wt = Wqkvt + z * 16384;
    int wave = threadIdx.x >> 6, lane = threadIdx.x & 63;
    int g = lane >> 4, c = lane & 15;
    int row0 = blockIdx.x * 64 + wave * 16;

    bf16x8 wf[8][4];
#pragma unroll
    for (int nt = 0; nt < 8; ++nt)
#pragma unroll
        for (int kk = 0; kk < 4; ++kk)
            wf[nt][kk] = *(const bf16x8*)(Wt + (nt * 16 + c) * 128 + kk * 32 + 8 * g);

    bf16x8 af[4];
#pragma unroll
    for (int kk = 0; kk < 4; ++kk)
        af[kk] = *(const bf16x8*)(xpe16 + (size_t)(row0 + c) * 128 + kk * 32 + 8 * g);

    f32x4 acc[8];
#pragma unroll
    for (int nt = 0; nt < 8; ++nt) acc[nt] = (f32x4){0.f, 0.f, 0.f, 0.f};
#pragma unroll
    for (int kk = 0; kk < 4; ++kk)
#pragma unroll
        for (int nt = 0; nt < 8; ++nt)
            acc[nt] = MFMA16(af[kk], wf[nt][kk], acc[nt]);

    int b = row0 >> 11;
    int t0 = (row0 & (T_SEQ - 1)) + 4 * g;
    if (z < 2) {
        short* dst = (z == 0) ? Qh : Kh;
        float sc = (z == 0) ? QSCALE : 1.0f;
#pragma unroll
        for (int nt = 0; nt < 8; ++nt) {
            int hb = nt * 4 + b;
#pragma unroll
            for (int r = 0; r < 4; ++r)
                dst[(size_t)(hb * T_SEQ + t0 + r) * 16 + c] = f2bf(acc[nt][r] * sc);
        }
    } else {
#pragma unroll
        for (int nt = 0; nt < 8; ++nt) {
            int hb = nt * 4 + b;
            bf16x4 v;
#pragma unroll
            for (int r = 0; r < 4; ++r) v[r] = f2bf(acc[nt][r]);
            *(bf16x4*)(Vs + (size_t)(hb * 16 + c) * T_SEQ + t0) = v;
        }
    }
}

// ---------------------------------------------------------------------------
// K2: column softmax denominators + V scaling. 256-thr blocks, 4 waves.
// Block (kc, hb): wave w owns 32 cols kw = kc*128 + w*32. Q staged in 256-row
// tiles (8 KB), double-buffered via global_load_lds. kc=0 longest, first.
// ---------------------------------------------------------------------------
__global__ __launch_bounds__(256) void k_csum(const short* __restrict__ Qh,
                                              const short* __restrict__ Kh,
                                              short* __restrict__ Vs) {
    __shared__ __align__(16) short Qt[2][4096];
    __shared__ float invl[128];
    const bf16x8 zz = {0, 0, 0, 0, 0, 0, 0, 0};
    const f32x4 z = {0.f, 0.f, 0.f, 0.f};

    int kc = blockIdx.x, hb = blockIdx.y;
    int tid = threadIdx.x;
    int wave = tid >> 6, lane = tid & 63;
    int g = lane >> 4, c = lane & 15;
    int kw = kc * 128 + wave * 32;
    const size_t hbT = (size_t)hb * T_SEQ;
    const short* Qg = Qh + hbT * 16;

    bf16x8 kfA = zz, kfB = zz;
    if (g < 2) {
        kfA = *(const bf16x8*)(Kh + (hbT + kw + c) * 16 + 8 * g);
        kfB = *(const bf16x8*)(Kh + (hbT + kw + 16 + c) * 16 + 8 * g);
    }

#define QSTAGE(bf, tq)                                                       \
    do {                                                                     \
        const short* src = Qg + (size_t)(tq) * 4096;                         \
        gload16(src + tid * 8, &Qt[bf][tid * 8]);                            \
        gload16(src + 2048 + tid * 8, &Qt[bf][2048 + tid * 8]);              \
    } while (0)

    int tstart = kc >> 1;                   // first 256-q tile with q >= kc*128
    QSTAGE(0, tstart);
    __syncthreads();

    float csA = 0.f, csB = 0.f;
    for (int tq = tstart; tq < 8; ++tq) {
        int buf = (tq - tstart) & 1;
        if (tq + 1 < 8) QSTAGE(buf ^ 1, tq + 1);
        const short* Qtb = &Qt[buf][0];
#pragma unroll
        for (int ss = 0; ss < 8; ++ss) {
            int q32 = tq * 256 + ss * 32;
            if (q32 + 31 < kw) continue;            // fully above diagonal
            bf16x8 qfa = zz, qfb = zz;
            if (g < 2) {
                qfa = *(const bf16x8*)(Qtb + (ss * 32 + c) * 16 + g * 8);
                qfb = *(const bf16x8*)(Qtb + (ss * 32 + 16 + c) * 16 + g * 8);
            }
            f32x4 sA1 = MFMA16(qfa, kfA, z);
            f32x4 sB1 = MFMA16(qfa, kfB, z);
            f32x4 sA2 = MFMA16(qfb, kfA, z);
            f32x4 sB2 = MFMA16(qfb, kfB, z);
            if (q32 >= kw + 32) {                   // fully below diagonal
#pragma unroll
                for (int r = 0; r < 4; ++r) {
                    csA += exp2_fast(sA1[r]) + exp2_fast(sA2[r]);
                    csB += exp2_fast(sB1[r]) + exp2_fast(sB2[r]);
                }
            } else {                                // diagonal region: mask
                int kA = kw + c, kB = kw + 16 + c;
#pragma unroll
                for (int r = 0; r < 4; ++r) {
                    int qa = q32 + 4 * g + r, qb = q32 + 16 + 4 * g + r;
                    csA += (qa >= kA) ? exp2_fast(sA1[r]) : 0.f;
                    csA += (qb >= kA) ? exp2_fast(sA2[r]) : 0.f;
                    csB += (qa >= kB) ? exp2_fast(sB1[r]) : 0.f;
                    csB += (qb >= kB) ? exp2_fast(sB2[r]) : 0.f;
                }
            }
        }
        __syncthreads();
    }
#undef QSTAGE

    csA += __shfl_xor(csA, 16);
    csA += __shfl_xor(csA, 32);
    csB += __shfl_xor(csB, 16);
    csB += __shfl_xor(csB, 32);
    if (lane < 32)
        invl[wave * 32 + lane] = 1.0f / ((lane < 16) ? csA : csB);
    __syncthreads();

    // scale V columns [kc*128, +128): 256 threads x bf16x8 = 16e x 128k
    int e = tid >> 4, kcol = (tid & 15) * 8;
    size_t vo = (size_t)(hb * 16 + e) * T_SEQ + kc * 128 + kcol;
    bf16x8 v = *(bf16x8*)(Vs + vo);
    bf16x8 o;
#pragma unroll
    for (int j = 0; j < 8; ++j) o[j] = f2bf(bf2f(v[j]) * invl[kcol + j]);
    *(bf16x8*)(Vs + vo) = o;
}

// ---------------------------------------------------------------------------
// K3: attention output. 256-thr blocks, 4 waves x 32 q-rows = 128-q chunk.
// Block (bx, hb): qn = 15-bx (longest first); K/V staged in 256-k tiles
// (16 KB: K linear + V e-major XOR-swizzled), double-buffered.
// O[q] = sum_{k<=q} exp2(S') * Vs (V pre-scaled by 1/colsum).
// ---------------------------------------------------------------------------
__global__ __launch_bounds__(256) void k_attn(const short* __restrict__ Qh,
                                              const short* __restrict__ Kh,
                                              const short* __restrict__ Vs,
                                              short* __restrict__ AObf) {
    __shared__ __align__(16) short Kt[2][4096];
    __shared__ __align__(16) short Vt[2][4096];
    const bf16x8 zz = {0, 0, 0, 0, 0, 0, 0, 0};
    const f32x4 z = {0.f, 0.f, 0.f, 0.f};

    int hb = blockIdx.y, h = hb >> 2, b = hb & 3;
    int qn = 15 - (int)blockIdx.x;          // 128-q chunk, longest first
    int tid = threadIdx.x;
    int wave = tid >> 6, lane = tid & 63;
    int g = lane >> 4, c = lane & 15;
    int q0w = qn * 128 + wave * 32;
    const size_t hbT = (size_t)hb * T_SEQ;
    const short* Kg = Kh + hbT * 16;
    const short* Vg = Vs + (size_t)hb * 16 * T_SEQ;

    bf16x8 qf0 = zz, qf1 = zz;
    if (g < 2) {
        qf0 = *(const bf16x8*)(Qh + (hbT + q0w + c) * 16 + 8 * g);
        qf1 = *(const bf16x8*)(Qh + (hbT + q0w + 16 + c) * 16 + 8 * g);
    }

    int nT = (qn >> 1) + 1;                 // 256-k tiles this block touches

    // V stage slot s (0..511): e = s>>5, granule j = (s&31) ^ (e&7)
#define STAGE(bf, kt)                                                        \
    do {                                                                     \
        int k0s = (kt) * 256;                                                \
        gload16(Kg + (size_t)k0s * 16 + tid * 8, &Kt[bf][tid * 8]);          \
        gload16(Kg + (size_t)k0s * 16 + 2048 + tid * 8,                      \
                &Kt[bf][2048 + tid * 8]);                                    \
        int e0 = tid >> 5, j0 = (tid & 31) ^ (e0 & 7);                       \
        gload16(Vg + (size_t)e0 * T_SEQ + k0s + j0 * 8, &Vt[bf][tid * 8]);   \
        int s1 = tid + 256;                                                  \
        int e1 = s1 >> 5, j1 = (s1 & 31) ^ (e1 & 7);                         \
        gload16(Vg + (size_t)e1 * T_SEQ + k0s + j1 * 8,                      \
                &Vt[bf][2048 + tid * 8]);                                    \
    } while (0)

    STAGE(0, 0);
    __syncthreads();

    f32x4 acc0 = z, acc1 = z;
    for (int t = 0; t < nT; ++t) {
        int buf = t & 1;
        if (t + 1 < nT) STAGE(buf ^ 1, t + 1);
        const short* Ktb = &Kt[buf][0];
        const short* Vtb = &Vt[buf][0];
#pragma unroll
        for (int ss = 0; ss < 8; ++ss) {
            int k32 = t * 256 + ss * 32;
            if (k32 > q0w + 31) continue;           // above causal range
            bf16x8 kf0 = zz, kf1 = zz;
            if (g < 2) {
                kf0 = *(const bf16x8*)(Ktb + (ss * 32 + c) * 16 + g * 8);
                kf1 = *(const bf16x8*)(Ktb + (ss * 32 + 16 + c) * 16 + g * 8);
            }
            int ja = ss * 4 + (g >> 1);             // granule in 32-granule row
            const short* vrow = Vtb + c * 256 + ((g & 1) << 2);
            bf16x4 v0 = *(const bf16x4*)(vrow + ((ja ^ (c & 7)) << 3));
            bf16x4 v1 = *(const bf16x4*)(vrow + (((ja + 2) ^ (c & 7)) << 3));
            f32x4 s0 = MFMA16(kf0, qf0, z);
            f32x4 s1 = MFMA16(kf1, qf0, z);
            f32x4 s2 = MFMA16(kf0, qf1, z);
            f32x4 s3 = MFMA16(kf1, qf1, z);
            bf16x8 aA, aB, vf;
            if (k32 + 31 <= q0w) {                  // full pair, no masking
#pragma unroll
                for (int r = 0; r < 4; ++r) {
                    aA[r] = bftrunc(exp2_fast(s0[r]));
                    aA[4 + r] = bftrunc(exp2_fast(s1[r]));
                    aB[r] = bftrunc(exp2_fast(s2[r]));
                    aB[4 + r] = bftrunc(exp2_fast(s3[r]));
                    vf[r] = v0[r];
                    vf[4 + r] = v1[r];
                }
            } else {                                // causal boundary: mask
                int qa = q0w + c, qb = q0w + 16 + c;
                int ka = k32 + 4 * g, kb = k32 + 16 + 4 * g;
#pragma unroll
                for (int r = 0; r < 4; ++r) {
                    aA[r] = (ka + r <= qa) ? bftrunc(exp2_fast(s0[r])) : (short)0;
                    aA[4 + r] = (kb + r <= qa) ? bftrunc(exp2_fast(s1[r])) : (short)0;
                    aB[r] = (ka + r <= qb) ? bftrunc(exp2_fast(s2[r])) : (short)0;
                    aB[4 + r] = (kb + r <= qb) ? bftrunc(exp2_fast(s3[r])) : (short)0;
                    vf[r] = v0[r];
                    vf[4 + r] = v1[r];
                }
            }
            acc0 = MFMA16(aA, vf, acc0);
            acc1 = MFMA16(aB, vf, acc1);
        }
        __syncthreads();
    }
#undef STAGE

#pragma unroll
    for (int r = 0; r < 4; ++r) {
        AObf[(size_t)(b * T_SEQ + q0w + 4 * g + r) * DMODEL + h * EHEAD + c] = f2bf(acc0[r]);
        AObf[(size_t)(b * T_SEQ + q0w + 16 + 4 * g + r) * DMODEL + h * EHEAD + c] = f2bf(acc1[r]);
    }
}

// ---------------------------------------------------------------------------
// K4: ff1 = relu(AO @ W1 + b1) -> F bf16 [8192][512]. W1t[n][k] in registers.
// ---------------------------------------------------------------------------
__global__ __launch_bounds__(256) void k_ff1(const short* __restrict__ AObf,
                                             const short* __restrict__ W1t,
                                             const float* __restrict__ b1,
                                             short* __restrict__ F) {
    int nc = blockIdx.y;
    int wave = threadIdx.x >> 6, lane = threadIdx.x & 63;
    int g = lane >> 4, c = lane & 15;
    int row0 = blockIdx.x * 64 + wave * 16;

    bf16x8 wf[8][4];
#pragma unroll
    for (int nt = 0; nt < 8; ++nt)
#pragma unroll
        for (int kk = 0; kk < 4; ++kk)
            wf[nt][kk] = *(const bf16x8*)(W1t + (nc * 128 + nt * 16 + c) * 128 + kk * 32 + 8 * g);

    bf16x8 af[4];
#pragma unroll
    for (int kk = 0; kk < 4; ++kk)
        af[kk] = *(const bf16x8*)(AObf + (size_t)(row0 + c) * 128 + kk * 32 + 8 * g);

    f32x4 acc[8];
#pragma unroll
    for (int nt = 0; nt < 8; ++nt) acc[nt] = (f32x4){0.f, 0.f, 0.f, 0.f};
#pragma unroll
    for (int kk = 0; kk < 4; ++kk)
#pragma unroll
        for (int nt = 0; nt < 8; ++nt)
            acc[nt] = MFMA16(af[kk], wf[nt][kk], acc[nt]);

#pragma unroll
    for (int nt = 0; nt < 8; ++nt) {
        int col = nc * 128 + nt * 16 + c;
        float bb = b1[col];
#pragma unroll
        for (int r = 0; r < 4; ++r)
            F[(size_t)(row0 + 4 * g + r) * DFF + col] = f2bf(fmaxf(acc[nt][r] + bb, 0.f));
    }
}

// ---------------------------------------------------------------------------
// K5: out = F @ W2 + b2 + xpe. W2t[n][k=512] in registers (32-col groups).
// ---------------------------------------------------------------------------
__global__ __launch_bounds__(256) void k_ff2(const short* __restrict__ F,
                                             const short* __restrict__ W2t,
                                             const float* __restrict__ b2,
                                             const float* __restrict__ xpe,
                                             float* __restrict__ out) {
    int ng = blockIdx.y;
    int wave = threadIdx.x >> 6, lane = threadIdx.x & 63;
    int g = lane >> 4, c = lane & 15;
    int row0 = blockIdx.x * 64 + wave * 16;

    bf16x8 wf[2][16];
#pragma unroll
    for (int nt = 0; nt < 2; ++nt)
#pragma unroll
        for (int kk = 0; kk < 16; ++kk)
            wf[nt][kk] = *(const bf16x8*)(W2t + (ng * 32 + nt * 16 + c) * 512 + kk * 32 + 8 * g);

    f32x4 acc[2];
    acc[0] = (f32x4){0.f, 0.f, 0.f, 0.f};
    acc[1] = (f32x4){0.f, 0.f, 0.f, 0.f};
#pragma unroll
    for (int kk = 0; kk < 16; ++kk) {
        bf16x8 a = *(const bf16x8*)(F + (size_t)(row0 + c) * 512 + kk * 32 + 8 * g);
        acc[0] = MFMA16(a, wf[0][kk], acc[0]);
        acc[1] = MFMA16(a, wf[1][kk], acc[1]);
    }
#pragma unroll
    for (int nt = 0; nt < 2; ++nt) {
        int col = ng * 32 + nt * 16 + c;
        float bb = b2[col];
#pragma unroll
        for (int r = 0; r < 4; ++r) {
            size_t o = (size_t)(row0 + 4 * g + r) * DMODEL + col;
            out[o] = acc[nt][r] + bb + xpe[o];
        }
    }
}

// ---------------------------------------------------------------------------
extern "C" void kernel_launch(void* const* d_in, const int* in_sizes, int n_in,
                              void* d_out, int out_size, void* d_ws, size_t ws_size,
                              hipStream_t stream) {
    const float* x  = (const float*)d_in[0];
    const float* WQ = (const float*)d_in[1];
    const float* WK = (const float*)d_in[2];
    const float* WV = (const float*)d_in[3];
    const float* W1 = (const float*)d_in[4];
    const float* b1 = (const float*)d_in[5];
    const float* W2 = (const float*)d_in[6];
    const float* b2 = (const float*)d_in[7];
    float* out = (float*)d_out;

    const size_t NTD = (size_t)BATCH * T_SEQ * DMODEL;   // 1048576
    float* xpe   = (float*)d_ws;
    short* xpe16 = (short*)(xpe + NTD);
    short* Qh    = xpe16 + NTD;
    short* Kh    = Qh + NTD;
    short* Vs    = Kh + NTD;
    short* AObf  = Vs + NTD;
    short* F     = AObf + NTD;                           // 8192*512 shorts
    short* Wqkvt = F + 4 * NTD;
    short* W1t   = Wqkvt + 3 * 16384;
    short* W2t   = W1t + 65536;

    k_pre<<<dim3(4800), dim3(256), 0, stream>>>(x, WQ, WK, WV, W1, W2,
                                                xpe, xpe16, Wqkvt, W1t, W2t);

    k_qkv<<<dim3(128, 3), dim3(256), 0, stream>>>(xpe16, Wqkvt, Qh, Kh, Vs);

    k_csum<<<dim3(16, 32), dim3(256), 0, stream>>>(Qh, Kh, Vs);

    k_attn<<<dim3(16, 32), dim3(256), 0, stream>>>(Qh, Kh, Vs, AObf);

    k_ff1<<<dim3(128, 4), dim3(256), 0, stream>>>(AObf, W1t, b1, F);

    k_ff2<<<dim3(128, 4), dim3(256), 0, stream>>>(F, W2t, b2, xpe, out);
}

// Round 9
// 88.267 us; speedup vs baseline: 1.1358x; 1.1358x over previous
//
#include <hip/hip_runtime.h>
#include <math.h>
#include <stdint.h>

#define T_SEQ 2048
#define BATCH 4
#define DMODEL 128
#define DFF 512
#define NHEAD 8
#define EHEAD 16

#define QSCALE (0.022097086912079608f * 1.4426950408889634f)   // rsqrt(T) * log2(e)

typedef __attribute__((ext_vector_type(8))) short bf16x8;
typedef __attribute__((ext_vector_type(4))) short bf16x4;
typedef __attribute__((ext_vector_type(4))) float f32x4;

__device__ __forceinline__ short f2bf(float f) {            // RNE
    uint32_t u = __float_as_uint(f);
    u = u + 0x7FFF + ((u >> 16) & 1);
    return (short)(u >> 16);
}
__device__ __forceinline__ short bftrunc(float f) {         // truncate (cheap)
    return (short)(__float_as_uint(f) >> 16);
}
__device__ __forceinline__ float bf2f(short s) {
    return __uint_as_float(((uint32_t)(unsigned short)s) << 16);
}
__device__ __forceinline__ float exp2_fast(float x) {       // raw v_exp_f32
#if __has_builtin(__builtin_amdgcn_exp2f)
    return __builtin_amdgcn_exp2f(x);
#else
    float r; asm("v_exp_f32 %0, %1" : "=v"(r) : "v"(x)); return r;
#endif
}

#define MFMA16(A, B, C) __builtin_amdgcn_mfma_f32_16x16x32_bf16(A, B, C, 0, 0, 0)

__device__ __forceinline__ void gload16(const void* g, void* l) {
    __builtin_amdgcn_global_load_lds(
        (const __attribute__((address_space(1))) void*)g,
        (__attribute__((address_space(3))) void*)l, 16, 0, 0);
}

// ---------------------------------------------------------------------------
// K0: xpe = x + PE (PE computed once per (t, f-pair), broadcast over batch);
// transpose+convert all weights to bf16.
// ---------------------------------------------------------------------------
__global__ __launch_bounds__(256) void k_pre(const float* __restrict__ x,
                                             const float* __restrict__ WQ,
                                             const float* __restrict__ WK,
                                             const float* __restrict__ WV,
                                             const float* __restrict__ W1,
                                             const float* __restrict__ W2,
                                             float* __restrict__ xpe,
                                             short* __restrict__ xpe16,
                                             short* __restrict__ Wqkvt,
                                             short* __restrict__ W1t,
                                             short* __restrict__ W2t) {
    int bid = blockIdx.x;
    int tid = threadIdx.x;
    if (bid < 512) {                        // PE over T*(D/2) = 131072 pairs
        int idx = bid * 256 + tid;
        int t = idx >> 6, fp = idx & 63;
        float dv = __expf(-(float)(2 * fp) * (9.210340371976184f / 128.0f));
        float ang = (float)t * dv;
        float sn = __sinf(ang), cs = __cosf(ang);
#pragma unroll
        for (int b = 0; b < 4; ++b) {
            size_t base = ((size_t)b * T_SEQ + t) * 128 + 2 * fp;
            float2 xv = *(const float2*)(x + base);
            float v0 = xv.x + sn, v1 = xv.y + cs;
            *(float2*)(xpe + base) = make_float2(v0, v1);
            uint32_t pk = (uint32_t)(unsigned short)f2bf(v0) |
                          ((uint32_t)(unsigned short)f2bf(v1) << 16);
            *(uint32_t*)(xpe16 + base) = pk;
        }
    } else if (bid < 704) {                 // WQ/WK/WV -> [n][k] bf16
        int m = (bid - 512) >> 6;
        int o = ((bid - 512) & 63) * 256 + tid;       // 0..16383
        int n = o >> 7, k = o & 127;
        const float* W = (m == 0) ? WQ : (m == 1) ? WK : WV;
        Wqkvt[m * 16384 + o] = f2bf(W[k * 128 + n]);
    } else if (bid < 960) {                 // W1 [128][512] -> W1t [512][128]
        int o = (bid - 704) * 256 + tid;    // 0..65535
        int n = o >> 7, k = o & 127;
        W1t[o] = f2bf(W1[k * 512 + n]);
    } else {                                // W2 [512][128] -> W2t [128][512]
        int o = (bid - 960) * 256 + tid;    // 0..65535
        int n = o >> 9, k = o & 511;
        W2t[o] = f2bf(W2[k * 128 + n]);
    }
}

// ---------------------------------------------------------------------------
// K1: QKV projection: bf16 MFMA GEMM, W in registers (Wt[n][k] bf16).
// z=0: Qh[hb][t][16] *= QSCALE; z=1: Kh[hb][t][16]; z=2: Vs[hb][e][T]
// ---------------------------------------------------------------------------
__global__ __launch_bounds__(256) void k_qkv(const short* __restrict__ xpe16,
                                             const short* __restrict__ Wqkvt,
                                             short* __restrict__ Qh,
                                             short* __restrict__ Kh,
                                             short* __restrict__ Vs) {
    int z = blockIdx.y;
    const short* Wt = Wqkvt + z * 16384;
    int wave = threadIdx.x >> 6, lane = threadIdx.x & 63;
    int g = lane >> 4, c = lane & 15;
    int row0 = blockIdx.x * 64 + wave * 16;

    bf16x8 wf[8][4];
#pragma unroll
    for (int nt = 0; nt < 8; ++nt)
#pragma unroll
        for (int kk = 0; kk < 4; ++kk)
            wf[nt][kk] = *(const bf16x8*)(Wt + (nt * 16 + c) * 128 + kk * 32 + 8 * g);

    bf16x8 af[4];
#pragma unroll
    for (int kk = 0; kk < 4; ++kk)
        af[kk] = *(const bf16x8*)(xpe16 + (size_t)(row0 + c) * 128 + kk * 32 + 8 * g);

    f32x4 acc[8];
#pragma unroll
    for (int nt = 0; nt < 8; ++nt) acc[nt] = (f32x4){0.f, 0.f, 0.f, 0.f};
#pragma unroll
    for (int kk = 0; kk < 4; ++kk)
#pragma unroll
        for (int nt = 0; nt < 8; ++nt)
            acc[nt] = MFMA16(af[kk], wf[nt][kk], acc[nt]);

    int b = row0 >> 11;
    int t0 = (row0 & (T_SEQ - 1)) + 4 * g;
    if (z < 2) {
        short* dst = (z == 0) ? Qh : Kh;
        float sc = (z == 0) ? QSCALE : 1.0f;
#pragma unroll
        for (int nt = 0; nt < 8; ++nt) {
            int hb = nt * 4 + b;
#pragma unroll
            for (int r = 0; r < 4; ++r)
                dst[(size_t)(hb * T_SEQ + t0 + r) * 16 + c] = f2bf(acc[nt][r] * sc);
        }
    } else {
#pragma unroll
        for (int nt = 0; nt < 8; ++nt) {
            int hb = nt * 4 + b;
            bf16x4 v;
#pragma unroll
            for (int r = 0; r < 4; ++r) v[r] = f2bf(acc[nt][r]);
            *(bf16x4*)(Vs + (size_t)(hb * 16 + c) * T_SEQ + t0) = v;
        }
    }
}

// ---------------------------------------------------------------------------
// K2: column softmax denominators + V scaling. 512-thr blocks (8 waves).
// Block (kc, hb) owns 128 k-cols; wave w = (strip s=w&3 -> 32 cols, half
// h=w>>2 -> q-slots {2h,2h+1} of each staged 128-q tile). Partial sums
// combined via LDS; block scales Vs columns [kc*128, +128) at the end.
// ---------------------------------------------------------------------------
__global__ __launch_bounds__(512, 4) void k_csum(const short* __restrict__ Qh,
                                                 const short* __restrict__ Kh,
                                                 short* __restrict__ Vs) {
    __shared__ __align__(16) short Qt[2][2048];
    __shared__ float csLds[8][32];
    __shared__ float invl[128];
    const bf16x8 zz = {0, 0, 0, 0, 0, 0, 0, 0};
    const f32x4 z = {0.f, 0.f, 0.f, 0.f};

    int kc = blockIdx.x, hb = blockIdx.y;
    int tid = threadIdx.x;
    int wave = tid >> 6, lane = tid & 63;
    int g = lane >> 4, c = lane & 15;
    int s = wave & 3, h = wave >> 2;
    int kw = kc * 128 + s * 32;
    const size_t hbT = (size_t)hb * T_SEQ;
    const short* Qg = Qh + hbT * 16;

    bf16x8 kfA = zz, kfB = zz;
    if (g < 2) {
        kfA = *(const bf16x8*)(Kh + (hbT + kw + c) * 16 + 8 * g);
        kfB = *(const bf16x8*)(Kh + (hbT + kw + 16 + c) * 16 + 8 * g);
    }

    int tstart = kc;                        // first 128-q tile with q >= kc*128
    if (tid < 256)
        gload16(Qg + (size_t)tstart * 2048 + tid * 8, &Qt[0][tid * 8]);
    __syncthreads();

    float csA = 0.f, csB = 0.f;
    for (int t = tstart; t < 16; ++t) {
        int buf = (t - tstart) & 1;
        if (t + 1 < 16 && tid < 256)
            gload16(Qg + (size_t)(t + 1) * 2048 + tid * 8, &Qt[buf ^ 1][tid * 8]);
        const short* Qtb = &Qt[buf][0];
#pragma unroll
        for (int sj = 0; sj < 2; ++sj) {
            int ss = 2 * h + sj;
            int q32 = t * 128 + ss * 32;
            if (q32 + 31 < kw) continue;            // fully above diagonal
            bf16x8 qfa = zz, qfb = zz;
            if (g < 2) {
                qfa = *(const bf16x8*)(Qtb + (ss * 32 + c) * 16 + g * 8);
                qfb = *(const bf16x8*)(Qtb + (ss * 32 + 16 + c) * 16 + g * 8);
            }
            f32x4 sA1 = MFMA16(qfa, kfA, z);
            f32x4 sB1 = MFMA16(qfa, kfB, z);
            f32x4 sA2 = MFMA16(qfb, kfA, z);
            f32x4 sB2 = MFMA16(qfb, kfB, z);
            if (q32 >= kw + 32) {                   // fully below diagonal
#pragma unroll
                for (int r = 0; r < 4; ++r) {
                    csA += exp2_fast(sA1[r]) + exp2_fast(sA2[r]);
                    csB += exp2_fast(sB1[r]) + exp2_fast(sB2[r]);
                }
            } else {                                // diagonal region: mask
                int kA = kw + c, kB = kw + 16 + c;
#pragma unroll
                for (int r = 0; r < 4; ++r) {
                    int qa = q32 + 4 * g + r, qb = q32 + 16 + 4 * g + r;
                    csA += (qa >= kA) ? exp2_fast(sA1[r]) : 0.f;
                    csA += (qb >= kA) ? exp2_fast(sA2[r]) : 0.f;
                    csB += (qa >= kB) ? exp2_fast(sB1[r]) : 0.f;
                    csB += (qb >= kB) ? exp2_fast(sB2[r]) : 0.f;
                }
            }
        }
        __syncthreads();
    }

    csA += __shfl_xor(csA, 16);
    csA += __shfl_xor(csA, 32);
    csB += __shfl_xor(csB, 16);
    csB += __shfl_xor(csB, 32);
    if (lane < 32) csLds[wave][lane] = (lane < 16) ? csA : csB;
    __syncthreads();
    if (tid < 128) {                        // strip = tid>>5, col-in-strip = tid&31
        int st = tid >> 5, col = tid & 31;
        invl[st * 32 + col] = 1.0f / (csLds[st][col] + csLds[st + 4][col]);
    }
    __syncthreads();
    if (tid < 256) {                        // scale V cols [kc*128, +128)
        int e = tid >> 4, kcol = (tid & 15) * 8;
        size_t vo = (size_t)(hb * 16 + e) * T_SEQ + kc * 128 + kcol;
        bf16x8 v = *(bf16x8*)(Vs + vo);
        bf16x8 o;
#pragma unroll
        for (int j = 0; j < 8; ++j) o[j] = f2bf(bf2f(v[j]) * invl[kcol + j]);
        *(bf16x8*)(Vs + vo) = o;
    }
}

// ---------------------------------------------------------------------------
// K3: attention output. 512-thr blocks (8 waves). Block (bx, hb): qn = 15-bx
// owns a 128-q chunk; wave w = (strip s=w&3 -> q0w = qn*128+s*32, half h=w>>2
// -> k-slots {2h,2h+1} of each staged 128-k tile). K linear + V e-major
// XOR-swizzled tiles double-buffered via global_load_lds. Partial O combined
// via LDS. O[q] = sum_{k<=q} exp2(S') * Vs (V pre-scaled by 1/colsum).
// ---------------------------------------------------------------------------
__global__ __launch_bounds__(512, 4) void k_attn(const short* __restrict__ Qh,
                                                 const short* __restrict__ Kh,
                                                 const short* __restrict__ Vs,
                                                 short* __restrict__ AObf) {
    __shared__ __align__(16) short Kt[2][2048];
    __shared__ __align__(16) short Vt[2][2048];
    const bf16x8 zz = {0, 0, 0, 0, 0, 0, 0, 0};
    const f32x4 z = {0.f, 0.f, 0.f, 0.f};

    int hb = blockIdx.y, h2 = hb >> 2, b = hb & 3;
    int qn = 15 - (int)blockIdx.x;          // 128-q chunk, longest first
    int tid = threadIdx.x;
    int wave = tid >> 6, lane = tid & 63;
    int g = lane >> 4, c = lane & 15;
    int s = wave & 3, h = wave >> 2;
    int q0w = qn * 128 + s * 32;
    const size_t hbT = (size_t)hb * T_SEQ;
    const short* Kg = Kh + hbT * 16;
    const short* Vg = Vs + (size_t)hb * 16 * T_SEQ;

    bf16x8 qf0 = zz, qf1 = zz;
    if (g < 2) {
        qf0 = *(const bf16x8*)(Qh + (hbT + q0w + c) * 16 + 8 * g);
        qf1 = *(const bf16x8*)(Qh + (hbT + q0w + 16 + c) * 16 + 8 * g);
    }

    int nT = qn + 1;                        // 128-k tiles this block touches

#define STAGE(bf, kt)                                                        \
    do {                                                                     \
        int k0s = (kt) * 128;                                                \
        if (tid < 256) {                                                     \
            gload16(Kg + (size_t)k0s * 16 + tid * 8, &Kt[bf][tid * 8]);      \
        } else {                                                             \
            int t2 = tid - 256;                                              \
            int e = t2 >> 4, jp = t2 & 15, j = jp ^ (e & 7);                 \
            gload16(Vg + (size_t)e * T_SEQ + k0s + j * 8, &Vt[bf][t2 * 8]);  \
        }                                                                    \
    } while (0)

    STAGE(0, 0);
    __syncthreads();

    f32x4 acc0 = z, acc1 = z;
    for (int t = 0; t < nT; ++t) {
        int buf = t & 1;
        if (t + 1 < nT) STAGE(buf ^ 1, t + 1);
        const short* Ktb = &Kt[buf][0];
        const short* Vtb = &Vt[buf][0];
#pragma unroll
        for (int sj = 0; sj < 2; ++sj) {
            int ss = 2 * h + sj;
            int k32 = t * 128 + ss * 32;
            if (k32 > q0w + 31) continue;           // above causal range
            bf16x8 kf0 = zz, kf1 = zz;
            if (g < 2) {
                kf0 = *(const bf16x8*)(Ktb + (ss * 32 + c) * 16 + g * 8);
                kf1 = *(const bf16x8*)(Ktb + (ss * 32 + 16 + c) * 16 + g * 8);
            }
            int ja = ss * 4 + (g >> 1);             // granule in 16-granule row
            const short* vrow = Vtb + c * 128 + ((g & 1) << 2);
            bf16x4 v0 = *(const bf16x4*)(vrow + ((ja ^ (c & 7)) << 3));
            bf16x4 v1 = *(const bf16x4*)(vrow + (((ja + 2) ^ (c & 7)) << 3));
            f32x4 s0 = MFMA16(kf0, qf0, z);
            f32x4 s1 = MFMA16(kf1, qf0, z);
            f32x4 s2 = MFMA16(kf0, qf1, z);
            f32x4 s3 = MFMA16(kf1, qf1, z);
            bf16x8 aA, aB, vf;
            if (k32 + 31 <= q0w) {                  // full pair, no masking
#pragma unroll
                for (int r = 0; r < 4; ++r) {
                    aA[r] = bftrunc(exp2_fast(s0[r]));
                    aA[4 + r] = bftrunc(exp2_fast(s1[r]));
                    aB[r] = bftrunc(exp2_fast(s2[r]));
                    aB[4 + r] = bftrunc(exp2_fast(s3[r]));
                    vf[r] = v0[r];
                    vf[4 + r] = v1[r];
                }
            } else {                                // causal boundary: mask
                int qa = q0w + c, qb = q0w + 16 + c;
                int ka = k32 + 4 * g, kb = k32 + 16 + 4 * g;
#pragma unroll
                for (int r = 0; r < 4; ++r) {
                    aA[r] = (ka + r <= qa) ? bftrunc(exp2_fast(s0[r])) : (short)0;
                    aA[4 + r] = (kb + r <= qa) ? bftrunc(exp2_fast(s1[r])) : (short)0;
                    aB[r] = (ka + r <= qb) ? bftrunc(exp2_fast(s2[r])) : (short)0;
                    aB[4 + r] = (kb + r <= qb) ? bftrunc(exp2_fast(s3[r])) : (short)0;
                    vf[r] = v0[r];
                    vf[4 + r] = v1[r];
                }
            }
            acc0 = MFMA16(aA, vf, acc0);
            acc1 = MFMA16(aB, vf, acc1);
        }
        __syncthreads();
    }
#undef STAGE

    // combine halves: h=1 waves dump partials to LDS (lane-contiguous per reg),
    // h=0 waves add and store.
    float* Of = (float*)&Kt[0][0];          // 8 KB, staging done
    if (h == 1) {
#pragma unroll
        for (int r = 0; r < 4; ++r) {
            Of[r * 256 + s * 64 + lane] = acc0[r];
            Of[(4 + r) * 256 + s * 64 + lane] = acc1[r];
        }
    }
    __syncthreads();
    if (h == 0) {
#pragma unroll
        for (int r = 0; r < 4; ++r) {
            acc0[r] += Of[r * 256 + s * 64 + lane];
            acc1[r] += Of[(4 + r) * 256 + s * 64 + lane];
        }
#pragma unroll
        for (int r = 0; r < 4; ++r) {
            AObf[(size_t)(b * T_SEQ + q0w + 4 * g + r) * DMODEL + h2 * EHEAD + c] = f2bf(acc0[r]);
            AObf[(size_t)(b * T_SEQ + q0w + 16 + 4 * g + r) * DMODEL + h2 * EHEAD + c] = f2bf(acc1[r]);
        }
    }
}

// ---------------------------------------------------------------------------
// K4: ff1 = relu(AO @ W1 + b1) -> F bf16 [8192][512]. W1t[n][k] in registers.
// ---------------------------------------------------------------------------
__global__ __launch_bounds__(256) void k_ff1(const short* __restrict__ AObf,
                                             const short* __restrict__ W1t,
                                             const float* __restrict__ b1,
                                             short* __restrict__ F) {
    int nc = blockIdx.y;
    int wave = threadIdx.x >> 6, lane = threadIdx.x & 63;
    int g = lane >> 4, c = lane & 15;
    int row0 = blockIdx.x * 64 + wave * 16;

    bf16x8 wf[8][4];
#pragma unroll
    for (int nt = 0; nt < 8; ++nt)
#pragma unroll
        for (int kk = 0; kk < 4; ++kk)
            wf[nt][kk] = *(const bf16x8*)(W1t + (nc * 128 + nt * 16 + c) * 128 + kk * 32 + 8 * g);

    bf16x8 af[4];
#pragma unroll
    for (int kk = 0; kk < 4; ++kk)
        af[kk] = *(const bf16x8*)(AObf + (size_t)(row0 + c) * 128 + kk * 32 + 8 * g);

    f32x4 acc[8];
#pragma unroll
    for (int nt = 0; nt < 8; ++nt) acc[nt] = (f32x4){0.f, 0.f, 0.f, 0.f};
#pragma unroll
    for (int kk = 0; kk < 4; ++kk)
#pragma unroll
        for (int nt = 0; nt < 8; ++nt)
            acc[nt] = MFMA16(af[kk], wf[nt][kk], acc[nt]);

#pragma unroll
    for (int nt = 0; nt < 8; ++nt) {
        int col = nc * 128 + nt * 16 + c;
        float bb = b1[col];
#pragma unroll
        for (int r = 0; r < 4; ++r)
            F[(size_t)(row0 + 4 * g + r) * DFF + col] = f2bf(fmaxf(acc[nt][r] + bb, 0.f));
    }
}

// ---------------------------------------------------------------------------
// K5: out = F @ W2 + b2 + xpe. W2t[n][k=512] in registers (32-col groups).
// ---------------------------------------------------------------------------
__global__ __launch_bounds__(256) void k_ff2(const short* __restrict__ F,
                                             const short* __restrict__ W2t,
                                             const float* __restrict__ b2,
                                             const float* __restrict__ xpe,
                                             float* __restrict__ out) {
    int ng = blockIdx.y;
    int wave = threadIdx.x >> 6, lane = threadIdx.x & 63;
    int g = lane >> 4, c = lane & 15;
    int row0 = blockIdx.x * 64 + wave * 16;

    bf16x8 wf[2][16];
#pragma unroll
    for (int nt = 0; nt < 2; ++nt)
#pragma unroll
        for (int kk = 0; kk < 16; ++kk)
            wf[nt][kk] = *(const bf16x8*)(W2t + (ng * 32 + nt * 16 + c) * 512 + kk * 32 + 8 * g);

    f32x4 acc[2];
    acc[0] = (f32x4){0.f, 0.f, 0.f, 0.f};
    acc[1] = (f32x4){0.f, 0.f, 0.f, 0.f};
#pragma unroll
    for (int kk = 0; kk < 16; ++kk) {
        bf16x8 a = *(const bf16x8*)(F + (size_t)(row0 + c) * 512 + kk * 32 + 8 * g);
        acc[0] = MFMA16(a, wf[0][kk], acc[0]);
        acc[1] = MFMA16(a, wf[1][kk], acc[1]);
    }
#pragma unroll
    for (int nt = 0; nt < 2; ++nt) {
        int col = ng * 32 + nt * 16 + c;
        float bb = b2[col];
#pragma unroll
        for (int r = 0; r < 4; ++r) {
            size_t o = (size_t)(row0 + 4 * g + r) * DMODEL + col;
            out[o] = acc[nt][r] + bb + xpe[o];
        }
    }
}

// ---------------------------------------------------------------------------
extern "C" void kernel_launch(void* const* d_in, const int* in_sizes, int n_in,
                              void* d_out, int out_size, void* d_ws, size_t ws_size,
                              hipStream_t stream) {
    const float* x  = (const float*)d_in[0];
    const float* WQ = (const float*)d_in[1];
    const float* WK = (const float*)d_in[2];
    const float* WV = (const float*)d_in[3];
    const float* W1 = (const float*)d_in[4];
    const float* b1 = (const float*)d_in[5];
    const float* W2 = (const float*)d_in[6];
    const float* b2 = (const float*)d_in[7];
    float* out = (float*)d_out;

    const size_t NTD = (size_t)BATCH * T_SEQ * DMODEL;   // 1048576
    float* xpe   = (float*)d_ws;
    short* xpe16 = (short*)(xpe + NTD);
    short* Qh    = xpe16 + NTD;
    short* Kh    = Qh + NTD;
    short* Vs    = Kh + NTD;
    short* AObf  = Vs + NTD;
    short* F     = AObf + NTD;                           // 8192*512 shorts
    short* Wqkvt = F + 4 * NTD;
    short* W1t   = Wqkvt + 3 * 16384;
    short* W2t   = W1t + 65536;

    k_pre<<<dim3(1216), dim3(256), 0, stream>>>(x, WQ, WK, WV, W1, W2,
                                                xpe, xpe16, Wqkvt, W1t, W2t);

    k_qkv<<<dim3(128, 3), dim3(256), 0, stream>>>(xpe16, Wqkvt, Qh, Kh, Vs);

    k_csum<<<dim3(16, 32), dim3(512), 0, stream>>>(Qh, Kh, Vs);

    k_attn<<<dim3(16, 32), dim3(512), 0, stream>>>(Qh, Kh, Vs, AObf);

    k_ff1<<<dim3(128, 4), dim3(256), 0, stream>>>(AObf, W1t, b1, F);

    k_ff2<<<dim3(128, 4), dim3(256), 0, stream>>>(F, W2t, b2, xpe, out);
}